// Round 16
// baseline (55.404 us; speedup 1.0000x reference)
//
#include <hip/hip_runtime.h>
#include <math.h>

#define NB 2
#define NMAPS 81          // 80 psi + 1 phi
#define NPSI 80
#define PIXELS 16384
#define OUT_STRIDE 4806

constexpr double PI_D = 3.14159265358979323846;

__device__ inline float2 cmulf(float2 a, float2 b) {
  return make_float2(a.x * b.x - a.y * b.y, a.x * b.y + a.y * b.x);
}

// DPP lane shuffle (VALU pipe, no LDS)
template <int CTRL>
__device__ inline float dppf(float v) {
  return __int_as_float(
      __builtin_amdgcn_update_dpp(0, __float_as_int(v), CTRL, 0xf, 0xf, true));
}

// xor-shuffle: masks 1,2,8 via DPP, 32 via permlane32_swap (VALU), else LDS.
__device__ inline float shx(float v, const int mask) {
  if (mask == 1) return dppf<0xB1>(v);
  if (mask == 2) return dppf<0x4E>(v);
  if (mask == 8) return dppf<0x128>(v);
  if (mask == 32) {
    auto r = __builtin_amdgcn_permlane32_swap(__float_as_uint(v),
                                              __float_as_uint(v), false, false);
    return __uint_as_float((threadIdx.x & 32) ? r[0] : r[1]);
  }
  return __shfl_xor(v, mask);
}

__device__ inline float wred64(float v) {
  int x;
  x = __builtin_amdgcn_update_dpp(0, __float_as_int(v), 0x111, 0xf, 0xf, true); v += __int_as_float(x);
  x = __builtin_amdgcn_update_dpp(0, __float_as_int(v), 0x112, 0xf, 0xf, true); v += __int_as_float(x);
  x = __builtin_amdgcn_update_dpp(0, __float_as_int(v), 0x114, 0xf, 0xf, true); v += __int_as_float(x);
  x = __builtin_amdgcn_update_dpp(0, __float_as_int(v), 0x118, 0xf, 0xf, true); v += __int_as_float(x);
  x = __builtin_amdgcn_update_dpp(0, __float_as_int(v), 0x142, 0xa, 0xf, true); v += __int_as_float(x);
  x = __builtin_amdgcn_update_dpp(0, __float_as_int(v), 0x143, 0xc, 0xf, true); v += __int_as_float(x);
  return __int_as_float(__builtin_amdgcn_readlane(__float_as_int(v), 63));
}

// ---------------- forward FFT of x: rows then cols (naive DFT) --------------
// Blocks >= NB*128 compute the sector mask instead (fused to save a launch).

__global__ __launch_bounds__(128) void k_fft_rows(const float* __restrict__ x,
                                                  float2* __restrict__ tx,
                                                  int* __restrict__ sector) {
  const int tid = threadIdx.x;
  const int blkid = blockIdx.x;
  if (blkid >= NB * 128) {
    int idx = (blkid - NB * 128) * 128 + tid;
    int i = idx >> 7, j = idx & 127;
    double fx = (double)(i < 64 ? i : i - 128) / 128.0;
    double fy = (double)(j < 64 ? j : j - 128) / 128.0;
    double kx = (2.0 * PI_D) * fx;
    double ky = (2.0 * PI_D) * fy;
    double r2 = kx * kx + ky * ky;
    const double h = PI_D / 2.0;
    int s = -1;
    if (r2 > h * h) {
      double th = atan2(ky, kx);
      th = fmod(th, PI_D);
      if (th < 0.0) th += PI_D;
      if (th < PI_D * 0.25) s = 0;
      else if (th < PI_D * 0.5) s = 1;
      else if (th < PI_D * 0.75) s = 2;
      else if (th < PI_D) s = 3;
    }
    sector[idx] = s;
    return;
  }
  __shared__ float row[128];
  __shared__ float2 wt[128];
  const int m = blkid & 127;
  const int b = blkid >> 7;
  {
    double ang = -(2.0 * PI_D / 128.0) * (double)tid;
    wt[tid] = make_float2((float)cos(ang), (float)sin(ang));
  }
  row[tid] = x[(b << 14) + (m << 7) + tid];
  __syncthreads();
  float ar = 0.f, ai = 0.f;
  int idx = 0;
  const int v = tid;
#pragma unroll 8
  for (int n = 0; n < 128; ++n) {
    float xv = row[n];
    float2 w = wt[idx];
    ar = fmaf(xv, w.x, ar);
    ai = fmaf(xv, w.y, ai);
    idx = (idx + v) & 127;
  }
  tx[(b << 14) + (m << 7) + tid] = make_float2(ar, ai);
}

__global__ __launch_bounds__(128) void k_fft_cols(const float2* __restrict__ tx,
                                                  float2* __restrict__ hatx) {
  __shared__ float2 col[128];
  __shared__ float2 wt[128];
  const int tid = threadIdx.x;
  const int v = blockIdx.x & 127;
  const int b = blockIdx.x >> 7;
  {
    double ang = -(2.0 * PI_D / 128.0) * (double)tid;
    wt[tid] = make_float2((float)cos(ang), (float)sin(ang));
  }
  col[tid] = tx[(b << 14) + (tid << 7) + v];
  __syncthreads();
  float ar = 0.f, ai = 0.f;
  int idx = 0;
  const int u = tid;
#pragma unroll 8
  for (int mm = 0; mm < 128; ++mm) {
    float2 z = col[mm];
    float2 w = wt[idx];
    ar += z.x * w.x - z.y * w.y;
    ai += z.x * w.y + z.y * w.x;
    idx = (idx + u) & 127;
  }
  hatx[(b << 14) + (tid << 7) + v] = make_float2(ar, ai);
}

// ---------------- shared 128-pt inverse FFT (radix-2 DIF) ---------
#define BFLY(z)                                     \
  {                                                 \
    float tx_ = shx((z).x, mask);                   \
    float ty_ = shx((z).y, mask);                   \
    float ax_ = fmaf(s, (z).x, tx_);                \
    float ay_ = fmaf(s, (z).y, ty_);                \
    (z).x = ax_ * we.x - ay_ * we.y;                \
    (z).y = ax_ * we.y + ay_ * we.x;                \
  }

__device__ inline void fft128_inv(float2& z0, float2& z1, float2& z2, float2& z3,
                                  const float2* __restrict__ wt, int l) {
  {
    float2 w = wt[l];
    float2 a0 = make_float2(z0.x + z1.x, z0.y + z1.y);
    float2 d0 = make_float2(z0.x - z1.x, z0.y - z1.y);
    z0 = a0;
    z1 = cmulf(d0, w);
    float2 a1 = make_float2(z2.x + z3.x, z2.y + z3.y);
    float2 d1 = make_float2(z2.x - z3.x, z2.y - z3.y);
    z2 = a1;
    z3 = cmulf(d1, w);
  }
#pragma unroll
  for (int mask = 32; mask >= 1; mask >>= 1) {
    float2 w = wt[(l & (mask - 1)) * (64 / mask)];
    const bool up = (l & mask) != 0;
    const float s = up ? -1.f : 1.f;
    const float2 we = up ? w : make_float2(1.f, 0.f);
    BFLY(z0);
    BFLY(z1);
    BFLY(z2);
    BFLY(z3);
  }
}

// ---------------- fused per-(b,filter) 2-D inverse FFT ----------------------
// Hermitian row-pass symmetrization (R15, verified): Re(ifft2(Z)) = ifft2(W),
// W[u,v] = (Z[u,v] + conj(Z[-u,-v]))/2; only rows 0..64 computed/stored.

__global__ __launch_bounds__(1024) void k_ifft2d(
    const float2* __restrict__ hatx,
    const float* __restrict__ psi_re, const float* __restrict__ psi_im,
    const float* __restrict__ phi_re, const float* __restrict__ phi_im,
    float* __restrict__ y, float2* __restrict__ meaninv,
    float* __restrict__ out) {
  __shared__ float2 Tsh[65 * 129];   // 67 KB
  __shared__ float2 wt[64];
  __shared__ float2 red16[16];
  const int tid = threadIdx.x;
  const int l = tid & 63;
  const int w = tid >> 6;
  const int mf = blockIdx.x;
  const int b = mf / NMAPS;
  const int f = mf - b * NMAPS;
  if (tid < 64) {
    double ang = (2.0 * PI_D / 128.0) * (double)tid;
    wt[tid] = make_float2((float)cos(ang), (float)sin(ang));
  }
  __syncthreads();
  const float2* hb2 = hatx + (b << 14);
  const float* fre = (f < NPSI) ? psi_re + ((size_t)f << 14) : phi_re;
  const float* fim = (f < NPSI) ? psi_im + ((size_t)f << 14) : phi_im;
  const int vr0 = (128 - l) & 127;   // mirror of v = l
  const int vr1 = (64 - l) & 127;    // mirror of v = l + 64
  // ---- row pass: W rows 0..63 in 2 rounds, row 64 by wave 0 ----
#define LOADZ(u, v) cmulf(hb2[((u) << 7) + (v)], \
    make_float2(fre[((u) << 7) + (v)], fim[((u) << 7) + (v)]))
  for (int r = 0; r < 2; ++r) {
    const int uA = r * 32 + (w << 1);
    const int uB = uA + 1;
    const int uAr = (128 - uA) & 127;
    const int uBr = 128 - uB;
    float2 dA0 = LOADZ(uA, l),        dA1 = LOADZ(uA, l + 64);
    float2 mA0 = LOADZ(uAr, vr0),     mA1 = LOADZ(uAr, vr1);
    float2 dB0 = LOADZ(uB, l),        dB1 = LOADZ(uB, l + 64);
    float2 mB0 = LOADZ(uBr, vr0),     mB1 = LOADZ(uBr, vr1);
    float2 wA0 = make_float2(0.5f * (dA0.x + mA0.x), 0.5f * (dA0.y - mA0.y));
    float2 wA1 = make_float2(0.5f * (dA1.x + mA1.x), 0.5f * (dA1.y - mA1.y));
    float2 wB0 = make_float2(0.5f * (dB0.x + mB0.x), 0.5f * (dB0.y - mB0.y));
    float2 wB1 = make_float2(0.5f * (dB1.x + mB1.x), 0.5f * (dB1.y - mB1.y));
    fft128_inv(wA0, wA1, wB0, wB1, wt, l);
    const int su = (uA >> 4) & 3;    // uB shares (uA even)
    Tsh[uA * 129 + (l ^ su)] = wA0;
    Tsh[uA * 129 + ((l ^ su) + 64)] = wA1;
    Tsh[uB * 129 + (l ^ su)] = wB0;
    Tsh[uB * 129 + ((l ^ su) + 64)] = wB1;
  }
  if (w == 0) {   // row 64 (self-mirror)
    float2 d0 = LOADZ(64, l), d1 = LOADZ(64, l + 64);
    float2 m0 = LOADZ(64, vr0), m1 = LOADZ(64, vr1);
    float2 w0 = make_float2(0.5f * (d0.x + m0.x), 0.5f * (d0.y - m0.y));
    float2 w1 = make_float2(0.5f * (d1.x + m1.x), 0.5f * (d1.y - m1.y));
    float2 w2 = w0, w3 = w1;
    fft128_inv(w0, w1, w2, w3, wt, l);
    Tsh[64 * 129 + l] = w0;          // su(64) = 0
    Tsh[64 * 129 + l + 64] = w1;
  }
#undef LOADZ
  __syncthreads();
  // ---- col pass: packed pairs; upper half via conjugate symmetry ----
  float s1 = 0.f, s2 = 0.f;
  float* yb = y + ((size_t)(b * NPSI + f) << 14);   // unused when f==NPSI
  const int m2 = __brev(l) >> 26;                   // bitrev6(l)
  const int rm = 64 - l;                            // l=0 -> row 64
  const int sl = (l >> 4) & 3;
  const int sm = (rm >> 4) & 3;
  const float sgn = (l == 0) ? 1.f : -1.f;
  const float2* rowL = &Tsh[l * 129];
  const float2* rowM = &Tsh[rm * 129];
  for (int r = 0; r < 2; ++r) {
    const int q0 = r * 64 + (w << 2);
    float2 a  = rowL[(q0    ) ^ sl], bb = rowL[(q0 + 1) ^ sl];
    float2 c  = rowL[(q0 + 2) ^ sl], d  = rowL[(q0 + 3) ^ sl];
    float2 am = rowM[(q0    ) ^ sm], bm = rowM[(q0 + 1) ^ sm];
    float2 cm = rowM[(q0 + 2) ^ sm], dm = rowM[(q0 + 3) ^ sm];
    float2 zA0 = make_float2(a.x - bb.y, a.y + bb.x);
    float2 zA1 = make_float2(fmaf(-sgn, bm.y, am.x), fmaf(sgn, am.y, bm.x));
    float2 zB0 = make_float2(c.x - d.y, c.y + d.x);
    float2 zB1 = make_float2(fmaf(-sgn, dm.y, cm.x), fmaf(sgn, cm.y, dm.x));
    fft128_inv(zA0, zA1, zB0, zB1, wt, l);
    const float sc = 1.f / 16384.f;
    const int nA0 = __brev(q0) >> 25;   // q0 multiple of 4
    float xA00 = zA0.x * sc, xA01 = zA0.y * sc;   // rows 2m2 / cols nA0, nA0+64
    float xA10 = zA1.x * sc, xA11 = zA1.y * sc;   // rows 2m2+1
    float xB00 = zB0.x * sc, xB01 = zB0.y * sc;   // cols nA0+32, nA0+96
    float xB10 = zB1.x * sc, xB11 = zB1.y * sc;
    if (f < NPSI) {
      xA00 = fmaxf(xA00, 0.f); xA01 = fmaxf(xA01, 0.f);
      xA10 = fmaxf(xA10, 0.f); xA11 = fmaxf(xA11, 0.f);
      xB00 = fmaxf(xB00, 0.f); xB01 = fmaxf(xB01, 0.f);
      xB10 = fmaxf(xB10, 0.f); xB11 = fmaxf(xB11, 0.f);
      *(float2*)(yb + ((nA0     ) << 7) + (m2 << 1)) = make_float2(xA00, xA10);
      *(float2*)(yb + ((nA0 + 64) << 7) + (m2 << 1)) = make_float2(xA01, xA11);
      *(float2*)(yb + ((nA0 + 32) << 7) + (m2 << 1)) = make_float2(xB00, xB10);
      *(float2*)(yb + ((nA0 + 96) << 7) + (m2 << 1)) = make_float2(xB01, xB11);
    }
    s1 += xA00 + xA01 + xA10 + xA11 + xB00 + xB01 + xB10 + xB11;
    s2 += xA00 * xA00 + xA01 * xA01 + xA10 * xA10 + xA11 * xA11 +
          xB00 * xB00 + xB01 * xB01 + xB10 * xB10 + xB11 * xB11;
  }
  float t1 = wred64(s1), t2 = wred64(s2);
  if (l == 0) red16[w] = make_float2(t1, t2);
  __syncthreads();
  if (w == 0) {
    float2 p = (l < 16) ? red16[l] : make_float2(0.f, 0.f);
    float S1 = wred64(p.x), S2 = wred64(p.y);
    if (l == 0) {
      float mean = S1 * (1.f / 16384.f);
      float msq  = S2 * (1.f / 16384.f);
      if (f < NPSI) {
        float var = fmaxf(msq - mean * mean, 0.f);
        meaninv[b * NPSI + f] = make_float2(mean, 1.f / (sqrtf(var) + 1e-6f));
      } else {
        out[b * OUT_STRIDE + 4800] = mean;
        out[b * OUT_STRIDE + 4801] = msq;
      }
    }
  }
}

// ---------------- correlations + tail ----------------
// Grid = 488 = 8*61; work id remapped so 61 consecutive works share one XCD.
// works [0, NB*240): 4 a1-maps x 5 shifts per work.
// y2 staged in TWO 68-row phases ([68][132] = 35.9 KB LDS) -> 4 blocks/CU
// (was 2 at 67.6 KB): doubles occupancy on a latency-bound kernel.
// works NB*240 + b: highpass sector energies for batch b. works >= 482: idle.
// y stored transposed ([n][m]); stored shifts (dr,dc):
// s0:(0,0) s1:(0,4) s2:(3,3) s3:(4,0) s4:(3,-3)
__global__ __launch_bounds__(256) void k_corrtail(
    const float* __restrict__ y, const float2* __restrict__ meaninv,
    const float2* __restrict__ hatx, const int* __restrict__ sector,
    float* __restrict__ out) {
  const int tid = threadIdx.x;
  const int l = tid & 63;
  const int w = tid >> 6;
  const int work = ((blockIdx.x & 7) * 61) + (blockIdx.x >> 3);
  if (work >= NB * 240) {
    const int b = work - NB * 240;
    if (b >= NB) return;
    __shared__ float red[4][4];
    float a0 = 0, a1 = 0, a2 = 0, a3 = 0;
    for (int k = tid; k < PIXELS; k += 256) {
      float2 hx = hatx[(b << 14) + k];
      float mag = hx.x * hx.x + hx.y * hx.y;
      int s = sector[k];
      if (s == 0) a0 += mag;
      else if (s == 1) a1 += mag;
      else if (s == 2) a2 += mag;
      else if (s == 3) a3 += mag;
    }
    a0 = wred64(a0); a1 = wred64(a1); a2 = wred64(a2); a3 = wred64(a3);
    if (l == 0) { red[w][0] = a0; red[w][1] = a1; red[w][2] = a2; red[w][3] = a3; }
    __syncthreads();
    if (tid < 4) {
      float tot = red[0][tid] + red[1][tid] + red[2][tid] + red[3][tid];
      out[b * OUT_STRIDE + 4802 + tid] = tot * (1.f / (16384.f * 16384.f));
    }
    return;
  }
  __shared__ float s2m[68 * 132];   // 35.9 KB: rows ph*64-4 .. ph*64+63
  __shared__ float redb[4 * 20];
  __shared__ float2 mi[5];
  const int b = work / 240;
  const int r_ = work - b * 240;
  const int jj = r_ >> 4;
  const int l1 = (r_ >> 2) & 3;
  const int l2 = r_ & 3;
  int j1 = 0, rem = jj;
  while (rem >= 5 - j1) { rem -= (5 - j1); ++j1; }
  const int j2 = j1 + rem;
  const int i1b = j1 * 16 + l1 * 4;
  const int i2 = j2 * 16 + l2 * 4;
  if (tid < 4) mi[tid] = meaninv[b * NPSI + i1b + tid];
  else if (tid == 4) mi[4] = meaninv[b * NPSI + i2];
  const float* __restrict__ y1 = y + ((size_t)(b * NPSI + i1b) << 14);
  const float* __restrict__ y2 = y + ((size_t)(b * NPSI + i2) << 14);
  const int r0 = tid >> 5;          // 0..7
  const int c4 = (tid & 31) << 2;   // 0,4,...,124
  const int bm4 = (c4 + 124) & 127;
  float acc[20];
#pragma unroll
  for (int o = 0; o < 20; ++o) acc[o] = 0.f;
  for (int ph = 0; ph < 2; ++ph) {
    const int rbase = ph * 64 - 4;
    // stage rows rbase..rbase+67 (wrapped): slot i = spatial (rbase+i)&127
    for (int qi = tid; qi < 68 * 32; qi += 256) {
      int i = qi >> 5;
      int c4s = (qi & 31) << 2;
      int srow = (rbase + i) & 127;
      *(float4*)&s2m[i * 132 + c4s] = *(const float4*)&y2[(srow << 7) + c4s];
    }
    __syncthreads();
    if (tid < 68) {
      *(float4*)&s2m[tid * 132 + 128] = *(const float4*)&s2m[tid * 132];
    }
    __syncthreads();
#pragma unroll 4
    for (int kk = 0; kk < 8; ++kk) {
      const int r = ph * 64 + kk * 8 + r0;   // spatial row (y1)
      const int i = kk * 8 + r0 + 4;         // slot of spatial row r
      const int rm0 = i * 132;
      const int rm3 = (i - 3) * 132;
      const int rm4 = (i - 4) * 132;
      float4 q0 = *(const float4*)&s2m[rm0 + c4];
      float4 q1 = *(const float4*)&s2m[rm0 + bm4];
      float4 q3 = *(const float4*)&s2m[rm4 + c4];
      float4 qa = *(const float4*)&s2m[rm3 + bm4];
      float4 qb = *(const float4*)&s2m[rm3 + bm4 + 4];
      float4 qd = *(const float4*)&s2m[rm3 + c4 + 4];
      const float u2x = qa.y, u2y = qa.z, u2z = qa.w, u2w = qb.x;   // shift s2
      const float u4x = qb.w, u4y = qd.x, u4z = qd.y, u4w = qd.z;   // shift s4
#pragma unroll
      for (int m = 0; m < 4; ++m) {
        float4 v = *(const float4*)&y1[(m << 14) + (r << 7) + c4];
        acc[m*5+0] = fmaf(v.w,q0.w,fmaf(v.z,q0.z,fmaf(v.y,q0.y,fmaf(v.x,q0.x,acc[m*5+0]))));
        acc[m*5+1] = fmaf(v.w,q1.w,fmaf(v.z,q1.z,fmaf(v.y,q1.y,fmaf(v.x,q1.x,acc[m*5+1]))));
        acc[m*5+2] = fmaf(v.w,u2w,fmaf(v.z,u2z,fmaf(v.y,u2y,fmaf(v.x,u2x,acc[m*5+2]))));
        acc[m*5+3] = fmaf(v.w,q3.w,fmaf(v.z,q3.z,fmaf(v.y,q3.y,fmaf(v.x,q3.x,acc[m*5+3]))));
        acc[m*5+4] = fmaf(v.w,u4w,fmaf(v.z,u4z,fmaf(v.y,u4y,fmaf(v.x,u4x,acc[m*5+4]))));
      }
    }
    __syncthreads();   // all reads done before restage / finish
  }
#pragma unroll
  for (int o = 0; o < 20; ++o) {
    float tot = wred64(acc[o]);
    if (l == 0) redb[w * 20 + o] = tot;
  }
  __syncthreads();
  if (tid < 20) {
    int m = tid / 5, s = tid - m * 5;
    float tot = redb[tid] + redb[20 + tid] + redb[40 + tid] + redb[60 + tid];
    float2 m1 = mi[m], m2 = mi[4];
    float c = m1.y * m2.y * (tot * (1.f / 16384.f) - m1.x * m2.x);
    int p = jj * 64 + l1 * 16 + l2 * 4 + m;
    out[b * OUT_STRIDE + s * 960 + p] = c;
  }
}

// ---------------- launch ----------------
extern "C" void kernel_launch(void* const* d_in, const int* in_sizes, int n_in,
                              void* d_out, int out_size, void* d_ws, size_t ws_size,
                              hipStream_t stream) {
  (void)in_sizes; (void)n_in; (void)out_size; (void)ws_size;
  const float* x      = (const float*)d_in[0];
  const float* psi_re = (const float*)d_in[1];
  const float* psi_im = (const float*)d_in[2];
  const float* phi_re = (const float*)d_in[3];
  const float* phi_im = (const float*)d_in[4];
  float* out = (float*)d_out;
  char* ws = (char*)d_ws;

  constexpr size_t TX_BYTES   = (size_t)NB * PIXELS * sizeof(float2);
  constexpr size_t HATX_OFF   = TX_BYTES;
  constexpr size_t HATX_BYTES = (size_t)NB * PIXELS * sizeof(float2);
  constexpr size_t Y_OFF      = HATX_OFF + HATX_BYTES;
  constexpr size_t Y_BYTES    = (size_t)NB * NPSI * PIXELS * sizeof(float);
  constexpr size_t MI_OFF     = Y_OFF + Y_BYTES;
  constexpr size_t MI_BYTES   = (size_t)NB * NPSI * sizeof(float2);
  constexpr size_t SEC_OFF    = MI_OFF + MI_BYTES;

  float2* tx       = (float2*)(ws);
  float2* hatx     = (float2*)(ws + HATX_OFF);
  float*  y        = (float*)(ws + Y_OFF);
  float2* meaninv  = (float2*)(ws + MI_OFF);
  int*    sector   = (int*)(ws + SEC_OFF);

  k_fft_rows<<<NB * 128 + 128, 128, 0, stream>>>(x, tx, sector);
  k_fft_cols<<<NB * 128, 128, 0, stream>>>(tx, hatx);
  k_ifft2d<<<NB * NMAPS, 1024, 0, stream>>>(hatx, psi_re, psi_im, phi_re, phi_im,
                                            y, meaninv, out);
  k_corrtail<<<488, 256, 0, stream>>>(y, meaninv, hatx, sector, out);
}

// Round 17
// 50.908 us; speedup vs baseline: 1.0883x; 1.0883x over previous
//
#include <hip/hip_runtime.h>
#include <math.h>

#define NB 2
#define NMAPS 81          // 80 psi + 1 phi
#define NPSI 80
#define PIXELS 16384
#define OUT_STRIDE 4806

constexpr double PI_D = 3.14159265358979323846;

__device__ inline float2 cmulf(float2 a, float2 b) {
  return make_float2(a.x * b.x - a.y * b.y, a.x * b.y + a.y * b.x);
}

// DPP lane shuffle (VALU pipe, no LDS)
template <int CTRL>
__device__ inline float dppf(float v) {
  return __int_as_float(
      __builtin_amdgcn_update_dpp(0, __float_as_int(v), CTRL, 0xf, 0xf, true));
}

// xor-shuffle: masks 1,2,8 via DPP, 32 via permlane32_swap (VALU), else LDS.
__device__ inline float shx(float v, const int mask) {
  if (mask == 1) return dppf<0xB1>(v);
  if (mask == 2) return dppf<0x4E>(v);
  if (mask == 8) return dppf<0x128>(v);
  if (mask == 32) {
    auto r = __builtin_amdgcn_permlane32_swap(__float_as_uint(v),
                                              __float_as_uint(v), false, false);
    return __uint_as_float((threadIdx.x & 32) ? r[0] : r[1]);
  }
  return __shfl_xor(v, mask);
}

__device__ inline float wred64(float v) {
  int x;
  x = __builtin_amdgcn_update_dpp(0, __float_as_int(v), 0x111, 0xf, 0xf, true); v += __int_as_float(x);
  x = __builtin_amdgcn_update_dpp(0, __float_as_int(v), 0x112, 0xf, 0xf, true); v += __int_as_float(x);
  x = __builtin_amdgcn_update_dpp(0, __float_as_int(v), 0x114, 0xf, 0xf, true); v += __int_as_float(x);
  x = __builtin_amdgcn_update_dpp(0, __float_as_int(v), 0x118, 0xf, 0xf, true); v += __int_as_float(x);
  x = __builtin_amdgcn_update_dpp(0, __float_as_int(v), 0x142, 0xa, 0xf, true); v += __int_as_float(x);
  x = __builtin_amdgcn_update_dpp(0, __float_as_int(v), 0x143, 0xc, 0xf, true); v += __int_as_float(x);
  return __int_as_float(__builtin_amdgcn_readlane(__float_as_int(v), 63));
}

// ---------------- 128-pt FFT cores (radix-2 DIF, shuffle-based) -------------
// Direction from twiddle table: wt[k]=e^{+2pi i k/128} inverse, conj forward.
// Output: storage index p holds X[bitrev7(p)]; lane l -> p=l (z0), p=l+64 (z1).

#define BFLY(z)                                     \
  {                                                 \
    float tx_ = shx((z).x, mask);                   \
    float ty_ = shx((z).y, mask);                   \
    float ax_ = fmaf(s, (z).x, tx_);                \
    float ay_ = fmaf(s, (z).y, ty_);                \
    (z).x = ax_ * we.x - ay_ * we.y;                \
    (z).y = ax_ * we.y + ay_ * we.x;                \
  }

__device__ inline void fft128_inv(float2& z0, float2& z1, float2& z2, float2& z3,
                                  const float2* __restrict__ wt, int l) {
  {
    float2 w = wt[l];
    float2 a0 = make_float2(z0.x + z1.x, z0.y + z1.y);
    float2 d0 = make_float2(z0.x - z1.x, z0.y - z1.y);
    z0 = a0;
    z1 = cmulf(d0, w);
    float2 a1 = make_float2(z2.x + z3.x, z2.y + z3.y);
    float2 d1 = make_float2(z2.x - z3.x, z2.y - z3.y);
    z2 = a1;
    z3 = cmulf(d1, w);
  }
#pragma unroll
  for (int mask = 32; mask >= 1; mask >>= 1) {
    float2 w = wt[(l & (mask - 1)) * (64 / mask)];
    const bool up = (l & mask) != 0;
    const float s = up ? -1.f : 1.f;
    const float2 we = up ? w : make_float2(1.f, 0.f);
    BFLY(z0);
    BFLY(z1);
    BFLY(z2);
    BFLY(z3);
  }
}

// 2-register (one line per wave) variant.
__device__ inline void fft128_2(float2& z0, float2& z1,
                                const float2* __restrict__ wt, int l) {
  {
    float2 w = wt[l];
    float2 a0 = make_float2(z0.x + z1.x, z0.y + z1.y);
    float2 d0 = make_float2(z0.x - z1.x, z0.y - z1.y);
    z0 = a0;
    z1 = cmulf(d0, w);
  }
#pragma unroll
  for (int mask = 32; mask >= 1; mask >>= 1) {
    float2 w = wt[(l & (mask - 1)) * (64 / mask)];
    const bool up = (l & mask) != 0;
    const float s = up ? -1.f : 1.f;
    const float2 we = up ? w : make_float2(1.f, 0.f);
    BFLY(z0);
    BFLY(z1);
  }
}

// ---------------- forward FFT of x: rows then cols (radix-2) ----------------
// Row kernel: blocks [0, NB*64): b = blk>>6, rows (blk&63)*2 + wave.
// Stores tx in bit-reversed storage order: tx[b][m][p] = X_m[brev7(p)].
// Blocks >= NB*64 compute the sector mask (fused to save a launch).

__global__ __launch_bounds__(128) void k_fft_rows(const float* __restrict__ x,
                                                  float2* __restrict__ tx,
                                                  int* __restrict__ sector) {
  const int tid = threadIdx.x;
  const int blkid = blockIdx.x;
  if (blkid >= NB * 64) {
    int idx = (blkid - NB * 64) * 128 + tid;
    int i = idx >> 7, j = idx & 127;
    double fx = (double)(i < 64 ? i : i - 128) / 128.0;
    double fy = (double)(j < 64 ? j : j - 128) / 128.0;
    double kx = (2.0 * PI_D) * fx;
    double ky = (2.0 * PI_D) * fy;
    double r2 = kx * kx + ky * ky;
    const double h = PI_D / 2.0;
    int s = -1;
    if (r2 > h * h) {
      double th = atan2(ky, kx);
      th = fmod(th, PI_D);
      if (th < 0.0) th += PI_D;
      if (th < PI_D * 0.25) s = 0;
      else if (th < PI_D * 0.5) s = 1;
      else if (th < PI_D * 0.75) s = 2;
      else if (th < PI_D) s = 3;
    }
    sector[idx] = s;
    return;
  }
  __shared__ float2 wtf[64];
  const int l = tid & 63;
  const int w = tid >> 6;
  const int b = blkid >> 6;
  const int m = ((blkid & 63) << 1) + w;
  if (tid < 64) {
    double ang = -(2.0 * PI_D / 128.0) * (double)tid;
    wtf[tid] = make_float2((float)cos(ang), (float)sin(ang));
  }
  __syncthreads();
  const float* xr = x + (b << 14) + (m << 7);
  float2 z0 = make_float2(xr[l], 0.f);
  float2 z1 = make_float2(xr[l + 64], 0.f);
  fft128_2(z0, z1, wtf, l);
  float2* to = tx + (b << 14) + (m << 7);
  to[l] = z0;
  to[l + 64] = z1;
}

// Col kernel: one 64-thread block per (b, storage col p). True freq col
// v = brev7(p). Output scattered to natural layout hatx[u][v].
__global__ __launch_bounds__(64) void k_fft_cols(const float2* __restrict__ tx,
                                                 float2* __restrict__ hatx) {
  __shared__ float2 wtf[64];
  const int l = threadIdx.x;
  const int p = blockIdx.x & 127;
  const int b = blockIdx.x >> 7;
  {
    double ang = -(2.0 * PI_D / 128.0) * (double)l;
    wtf[l] = make_float2((float)cos(ang), (float)sin(ang));
  }
  __syncthreads();
  const float2* ti = tx + (b << 14) + p;
  float2 z0 = ti[l << 7];
  float2 z1 = ti[(l + 64) << 7];
  fft128_2(z0, z1, wtf, l);
  const int v = __brev(p) >> 25;
  const int u0 = __brev(l) >> 25;   // even; brev7(l+64) = u0+1
  float2* ho = hatx + (b << 14) + v;
  ho[u0 << 7] = z0;
  ho[(u0 + 1) << 7] = z1;
}

// ---------------- fused per-(b,filter) 2-D inverse FFT ----------------------
// Hermitian row-pass symmetrization (R15, verified): Re(ifft2(Z)) = ifft2(W),
// W[u,v] = (Z[u,v] + conj(Z[-u,-v]))/2; only rows 0..64 computed/stored.

__global__ __launch_bounds__(1024) void k_ifft2d(
    const float2* __restrict__ hatx,
    const float* __restrict__ psi_re, const float* __restrict__ psi_im,
    const float* __restrict__ phi_re, const float* __restrict__ phi_im,
    float* __restrict__ y, float2* __restrict__ meaninv,
    float* __restrict__ out) {
  __shared__ float2 Tsh[65 * 129];   // 67 KB
  __shared__ float2 wt[64];
  __shared__ float2 red16[16];
  const int tid = threadIdx.x;
  const int l = tid & 63;
  const int w = tid >> 6;
  const int mf = blockIdx.x;
  const int b = mf / NMAPS;
  const int f = mf - b * NMAPS;
  if (tid < 64) {
    double ang = (2.0 * PI_D / 128.0) * (double)tid;
    wt[tid] = make_float2((float)cos(ang), (float)sin(ang));
  }
  __syncthreads();
  const float2* hb2 = hatx + (b << 14);
  const float* fre = (f < NPSI) ? psi_re + ((size_t)f << 14) : phi_re;
  const float* fim = (f < NPSI) ? psi_im + ((size_t)f << 14) : phi_im;
  const int vr0 = (128 - l) & 127;   // mirror of v = l
  const int vr1 = (64 - l) & 127;    // mirror of v = l + 64
  // ---- row pass: W rows 0..63 in 2 rounds, row 64 by wave 0 ----
#define LOADZ(u, v) cmulf(hb2[((u) << 7) + (v)], \
    make_float2(fre[((u) << 7) + (v)], fim[((u) << 7) + (v)]))
  for (int r = 0; r < 2; ++r) {
    const int uA = r * 32 + (w << 1);
    const int uB = uA + 1;
    const int uAr = (128 - uA) & 127;
    const int uBr = 128 - uB;
    float2 dA0 = LOADZ(uA, l),        dA1 = LOADZ(uA, l + 64);
    float2 mA0 = LOADZ(uAr, vr0),     mA1 = LOADZ(uAr, vr1);
    float2 dB0 = LOADZ(uB, l),        dB1 = LOADZ(uB, l + 64);
    float2 mB0 = LOADZ(uBr, vr0),     mB1 = LOADZ(uBr, vr1);
    float2 wA0 = make_float2(0.5f * (dA0.x + mA0.x), 0.5f * (dA0.y - mA0.y));
    float2 wA1 = make_float2(0.5f * (dA1.x + mA1.x), 0.5f * (dA1.y - mA1.y));
    float2 wB0 = make_float2(0.5f * (dB0.x + mB0.x), 0.5f * (dB0.y - mB0.y));
    float2 wB1 = make_float2(0.5f * (dB1.x + mB1.x), 0.5f * (dB1.y - mB1.y));
    fft128_inv(wA0, wA1, wB0, wB1, wt, l);
    const int su = (uA >> 4) & 3;    // uB shares (uA even)
    Tsh[uA * 129 + (l ^ su)] = wA0;
    Tsh[uA * 129 + ((l ^ su) + 64)] = wA1;
    Tsh[uB * 129 + (l ^ su)] = wB0;
    Tsh[uB * 129 + ((l ^ su) + 64)] = wB1;
  }
  if (w == 0) {   // row 64 (self-mirror)
    float2 d0 = LOADZ(64, l), d1 = LOADZ(64, l + 64);
    float2 m0 = LOADZ(64, vr0), m1 = LOADZ(64, vr1);
    float2 w0 = make_float2(0.5f * (d0.x + m0.x), 0.5f * (d0.y - m0.y));
    float2 w1 = make_float2(0.5f * (d1.x + m1.x), 0.5f * (d1.y - m1.y));
    float2 w2 = w0, w3 = w1;
    fft128_inv(w0, w1, w2, w3, wt, l);
    Tsh[64 * 129 + l] = w0;          // su(64) = 0
    Tsh[64 * 129 + l + 64] = w1;
  }
#undef LOADZ
  __syncthreads();
  // ---- col pass: packed pairs; upper half via conjugate symmetry ----
  float s1 = 0.f, s2 = 0.f;
  float* yb = y + ((size_t)(b * NPSI + f) << 14);   // unused when f==NPSI
  const int m2 = __brev(l) >> 26;                   // bitrev6(l)
  const int rm = 64 - l;                            // l=0 -> row 64
  const int sl = (l >> 4) & 3;
  const int sm = (rm >> 4) & 3;
  const float sgn = (l == 0) ? 1.f : -1.f;
  const float2* rowL = &Tsh[l * 129];
  const float2* rowM = &Tsh[rm * 129];
  for (int r = 0; r < 2; ++r) {
    const int q0 = r * 64 + (w << 2);
    float2 a  = rowL[(q0    ) ^ sl], bb = rowL[(q0 + 1) ^ sl];
    float2 c  = rowL[(q0 + 2) ^ sl], d  = rowL[(q0 + 3) ^ sl];
    float2 am = rowM[(q0    ) ^ sm], bm = rowM[(q0 + 1) ^ sm];
    float2 cm = rowM[(q0 + 2) ^ sm], dm = rowM[(q0 + 3) ^ sm];
    float2 zA0 = make_float2(a.x - bb.y, a.y + bb.x);
    float2 zA1 = make_float2(fmaf(-sgn, bm.y, am.x), fmaf(sgn, am.y, bm.x));
    float2 zB0 = make_float2(c.x - d.y, c.y + d.x);
    float2 zB1 = make_float2(fmaf(-sgn, dm.y, cm.x), fmaf(sgn, cm.y, dm.x));
    fft128_inv(zA0, zA1, zB0, zB1, wt, l);
    const float sc = 1.f / 16384.f;
    const int nA0 = __brev(q0) >> 25;   // q0 multiple of 4
    float xA00 = zA0.x * sc, xA01 = zA0.y * sc;   // rows 2m2 / cols nA0, nA0+64
    float xA10 = zA1.x * sc, xA11 = zA1.y * sc;   // rows 2m2+1
    float xB00 = zB0.x * sc, xB01 = zB0.y * sc;   // cols nA0+32, nA0+96
    float xB10 = zB1.x * sc, xB11 = zB1.y * sc;
    if (f < NPSI) {
      xA00 = fmaxf(xA00, 0.f); xA01 = fmaxf(xA01, 0.f);
      xA10 = fmaxf(xA10, 0.f); xA11 = fmaxf(xA11, 0.f);
      xB00 = fmaxf(xB00, 0.f); xB01 = fmaxf(xB01, 0.f);
      xB10 = fmaxf(xB10, 0.f); xB11 = fmaxf(xB11, 0.f);
      *(float2*)(yb + ((nA0     ) << 7) + (m2 << 1)) = make_float2(xA00, xA10);
      *(float2*)(yb + ((nA0 + 64) << 7) + (m2 << 1)) = make_float2(xA01, xA11);
      *(float2*)(yb + ((nA0 + 32) << 7) + (m2 << 1)) = make_float2(xB00, xB10);
      *(float2*)(yb + ((nA0 + 96) << 7) + (m2 << 1)) = make_float2(xB01, xB11);
    }
    s1 += xA00 + xA01 + xA10 + xA11 + xB00 + xB01 + xB10 + xB11;
    s2 += xA00 * xA00 + xA01 * xA01 + xA10 * xA10 + xA11 * xA11 +
          xB00 * xB00 + xB01 * xB01 + xB10 * xB10 + xB11 * xB11;
  }
  float t1 = wred64(s1), t2 = wred64(s2);
  if (l == 0) red16[w] = make_float2(t1, t2);
  __syncthreads();
  if (w == 0) {
    float2 p = (l < 16) ? red16[l] : make_float2(0.f, 0.f);
    float S1 = wred64(p.x), S2 = wred64(p.y);
    if (l == 0) {
      float mean = S1 * (1.f / 16384.f);
      float msq  = S2 * (1.f / 16384.f);
      if (f < NPSI) {
        float var = fmaxf(msq - mean * mean, 0.f);
        meaninv[b * NPSI + f] = make_float2(mean, 1.f / (sqrtf(var) + 1e-6f));
      } else {
        out[b * OUT_STRIDE + 4800] = mean;
        out[b * OUT_STRIDE + 4801] = msq;
      }
    }
  }
}

// ---------------- correlations + tail ----------------
// Grid = 488 = 8*61; work id remapped so 61 consecutive works share one XCD.
// works [0, NB*240): 4 a1-maps x 5 shifts per work.
// works NB*240 + b: highpass sector energies for batch b. works >= 482: idle.
// y stored transposed ([n][m]); stored shifts (dr,dc):
// s0:(0,0) s1:(0,4) s2:(3,3) s3:(4,0) s4:(3,-3)
__global__ __launch_bounds__(256) void k_corrtail(
    const float* __restrict__ y, const float2* __restrict__ meaninv,
    const float2* __restrict__ hatx, const int* __restrict__ sector,
    float* __restrict__ out) {
  const int tid = threadIdx.x;
  const int l = tid & 63;
  const int w = tid >> 6;
  const int work = ((blockIdx.x & 7) * 61) + (blockIdx.x >> 3);
  if (work >= NB * 240) {
    const int b = work - NB * 240;
    if (b >= NB) return;
    __shared__ float red[4][4];
    float a0 = 0, a1 = 0, a2 = 0, a3 = 0;
    for (int k = tid; k < PIXELS; k += 256) {
      float2 hx = hatx[(b << 14) + k];
      float mag = hx.x * hx.x + hx.y * hx.y;
      int s = sector[k];
      if (s == 0) a0 += mag;
      else if (s == 1) a1 += mag;
      else if (s == 2) a2 += mag;
      else if (s == 3) a3 += mag;
    }
    a0 = wred64(a0); a1 = wred64(a1); a2 = wred64(a2); a3 = wred64(a3);
    if (l == 0) { red[w][0] = a0; red[w][1] = a1; red[w][2] = a2; red[w][3] = a3; }
    __syncthreads();
    if (tid < 4) {
      float tot = red[0][tid] + red[1][tid] + red[2][tid] + red[3][tid];
      out[b * OUT_STRIDE + 4802 + tid] = tot * (1.f / (16384.f * 16384.f));
    }
    return;
  }
  __shared__ float s2m[128 * 132];  // y2 padded: cols 128..131 = cols 0..3
  __shared__ float redb[4 * 20];
  __shared__ float2 mi[5];
  const int b = work / 240;
  const int r_ = work - b * 240;
  const int jj = r_ >> 4;
  const int l1 = (r_ >> 2) & 3;
  const int l2 = r_ & 3;
  int j1 = 0, rem = jj;
  while (rem >= 5 - j1) { rem -= (5 - j1); ++j1; }
  const int j2 = j1 + rem;
  const int i1b = j1 * 16 + l1 * 4;
  const int i2 = j2 * 16 + l2 * 4;
  if (tid < 4) mi[tid] = meaninv[b * NPSI + i1b + tid];
  else if (tid == 4) mi[4] = meaninv[b * NPSI + i2];
  const float* __restrict__ y1 = y + ((size_t)(b * NPSI + i1b) << 14);
  const float* __restrict__ y2 = y + ((size_t)(b * NPSI + i2) << 14);
  const int r0 = tid >> 5;          // 0..7
  const int c4 = (tid & 31) << 2;   // 0,4,...,124
#pragma unroll
  for (int k = 0; k < 16; ++k) {
    int row = k * 8 + r0;
    *(float4*)&s2m[row * 132 + c4] = *(const float4*)&y2[(row << 7) + c4];
  }
  __syncthreads();
  if (tid < 128) {
    *(float4*)&s2m[tid * 132 + 128] = *(const float4*)&s2m[tid * 132];
  }
  __syncthreads();
  const int bm4 = (c4 + 124) & 127;
  float acc[20];
#pragma unroll
  for (int o = 0; o < 20; ++o) acc[o] = 0.f;
#pragma unroll 4
  for (int k = 0; k < 16; ++k) {
    const int r = k * 8 + r0;
    const int rm0 = r * 132;
    const int rm3 = ((r + 125) & 127) * 132;
    const int rm4 = ((r + 124) & 127) * 132;
    float4 q0 = *(const float4*)&s2m[rm0 + c4];
    float4 q1 = *(const float4*)&s2m[rm0 + bm4];
    float4 q3 = *(const float4*)&s2m[rm4 + c4];
    float4 qa = *(const float4*)&s2m[rm3 + bm4];
    float4 qb = *(const float4*)&s2m[rm3 + bm4 + 4];
    float4 qd = *(const float4*)&s2m[rm3 + c4 + 4];
    const float u2x = qa.y, u2y = qa.z, u2z = qa.w, u2w = qb.x;   // shift s2
    const float u4x = qb.w, u4y = qd.x, u4z = qd.y, u4w = qd.z;   // shift s4
#pragma unroll
    for (int m = 0; m < 4; ++m) {
      float4 v = *(const float4*)&y1[(m << 14) + (r << 7) + c4];
      acc[m*5+0] = fmaf(v.w,q0.w,fmaf(v.z,q0.z,fmaf(v.y,q0.y,fmaf(v.x,q0.x,acc[m*5+0]))));
      acc[m*5+1] = fmaf(v.w,q1.w,fmaf(v.z,q1.z,fmaf(v.y,q1.y,fmaf(v.x,q1.x,acc[m*5+1]))));
      acc[m*5+2] = fmaf(v.w,u2w,fmaf(v.z,u2z,fmaf(v.y,u2y,fmaf(v.x,u2x,acc[m*5+2]))));
      acc[m*5+3] = fmaf(v.w,q3.w,fmaf(v.z,q3.z,fmaf(v.y,q3.y,fmaf(v.x,q3.x,acc[m*5+3]))));
      acc[m*5+4] = fmaf(v.w,u4w,fmaf(v.z,u4z,fmaf(v.y,u4y,fmaf(v.x,u4x,acc[m*5+4]))));
    }
  }
#pragma unroll
  for (int o = 0; o < 20; ++o) {
    float tot = wred64(acc[o]);
    if (l == 0) redb[w * 20 + o] = tot;
  }
  __syncthreads();
  if (tid < 20) {
    int m = tid / 5, s = tid - m * 5;
    float tot = redb[tid] + redb[20 + tid] + redb[40 + tid] + redb[60 + tid];
    float2 m1 = mi[m], m2 = mi[4];
    float c = m1.y * m2.y * (tot * (1.f / 16384.f) - m1.x * m2.x);
    int p = jj * 64 + l1 * 16 + l2 * 4 + m;
    out[b * OUT_STRIDE + s * 960 + p] = c;
  }
}

// ---------------- launch ----------------
extern "C" void kernel_launch(void* const* d_in, const int* in_sizes, int n_in,
                              void* d_out, int out_size, void* d_ws, size_t ws_size,
                              hipStream_t stream) {
  (void)in_sizes; (void)n_in; (void)out_size; (void)ws_size;
  const float* x      = (const float*)d_in[0];
  const float* psi_re = (const float*)d_in[1];
  const float* psi_im = (const float*)d_in[2];
  const float* phi_re = (const float*)d_in[3];
  const float* phi_im = (const float*)d_in[4];
  float* out = (float*)d_out;
  char* ws = (char*)d_ws;

  constexpr size_t TX_BYTES   = (size_t)NB * PIXELS * sizeof(float2);
  constexpr size_t HATX_OFF   = TX_BYTES;
  constexpr size_t HATX_BYTES = (size_t)NB * PIXELS * sizeof(float2);
  constexpr size_t Y_OFF      = HATX_OFF + HATX_BYTES;
  constexpr size_t Y_BYTES    = (size_t)NB * NPSI * PIXELS * sizeof(float);
  constexpr size_t MI_OFF     = Y_OFF + Y_BYTES;
  constexpr size_t MI_BYTES   = (size_t)NB * NPSI * sizeof(float2);
  constexpr size_t SEC_OFF    = MI_OFF + MI_BYTES;

  float2* tx       = (float2*)(ws);
  float2* hatx     = (float2*)(ws + HATX_OFF);
  float*  y        = (float*)(ws + Y_OFF);
  float2* meaninv  = (float2*)(ws + MI_OFF);
  int*    sector   = (int*)(ws + SEC_OFF);

  k_fft_rows<<<NB * 64 + 128, 128, 0, stream>>>(x, tx, sector);
  k_fft_cols<<<NB * 128, 64, 0, stream>>>(tx, hatx);
  k_ifft2d<<<NB * NMAPS, 1024, 0, stream>>>(hatx, psi_re, psi_im, phi_re, phi_im,
                                            y, meaninv, out);
  k_corrtail<<<488, 256, 0, stream>>>(y, meaninv, hatx, sector, out);
}